// Round 21
// baseline (178.687 us; speedup 1.0000x reference)
//
#include <hip/hip_runtime.h>

#define NF 128
#define NC 64
#define NBMAX 512          // max dst-buckets (N/256 = 391 for N=100000)
#define TPART 8192         // edges per k_part block
#define BCAP 5120          // fixed bucket capacity: mean 4092 + 16 sigma
#define WPITCH 136         // LDS W^T pitch in bf16: 272B rows, 2-way banks (free)

static inline size_t alignup(size_t x){ return (x + 255) & ~(size_t)255; }

typedef __attribute__((ext_vector_type(8))) short bf16x8;
typedef __attribute__((ext_vector_type(4))) float f32x4;
typedef __attribute__((ext_vector_type(16))) int i32x16;

__device__ __forceinline__ unsigned short f2bf(float f){
  unsigned u = __float_as_uint(f);
  u += 0x7fffu + ((u >> 16) & 1u);       // round-to-nearest-even
  return (unsigned short)(u >> 16);
}
__device__ __forceinline__ float bflo(unsigned u){ return __uint_as_float(u << 16); }
__device__ __forceinline__ float bfhi(unsigned u){ return __uint_as_float(u & 0xffff0000u); }

// issue 8 edge records into SGPRs (no wait); SMEM needs only dword alignment
__device__ __forceinline__ void sload16_issue(i32x16& r, const int2* p){
  asm volatile("s_load_dwordx16 %0, %1, 0x0" : "=s"(r) : "s"(p));
}
__device__ __forceinline__ void swait2(i32x16& a, i32x16& b){
  asm volatile("s_waitcnt lgkmcnt(0)" : "+s"(a), "+s"(b));
}
__device__ __forceinline__ void swait4(i32x16& a, i32x16& b, i32x16& c, i32x16& d){
  asm volatile("s_waitcnt lgkmcnt(0)" : "+s"(a), "+s"(b), "+s"(c), "+s"(d));
}

// ---------- 0. pre-convert weights to transposed bf16 + init bucket cursors ----------
__global__ __launch_bounds__(256) void k_cvtW(const float* __restrict__ W0, const float* __restrict__ W1,
                                              unsigned short* __restrict__ W0t, unsigned short* __restrict__ W1t,
                                              int* __restrict__ bcur, int NB){
  int t = blockIdx.x*256 + threadIdx.x;
  if (t < NB) bcur[t] = t * BCAP;             // fixed-capacity bases
  if (t < 128*128){ int k = t >> 7, c = t & 127; W0t[c*128 + k] = f2bf(W0[t]); }
  int u = t - 128*128;
  if (u >= 0 && u < 128*64){ int k = u >> 6, c = u & 63; W1t[c*128 + k] = f2bf(W1[u]); }
}

// ---------- 1. FUSED: partition (blocks < PB)  ||  GEMM1 MFMA (blocks >= PB) ----------
__global__ __launch_bounds__(1024, 4) void k_partg(const int* __restrict__ src, const int* __restrict__ dst,
    const float* __restrict__ w, int* __restrict__ bcur, int2* __restrict__ part, int E, int NB, int PB,
    const float* __restrict__ A, const unsigned short* __restrict__ Wg, unsigned short* __restrict__ Y, int n){
  __shared__ __align__(16) char smem[TPART*8 + NBMAX*16];   // 72 KB
  const int t = threadIdx.x;
  if ((int)blockIdx.x < PB){
    // ---- partition role ----
    int2* stage = (int2*)smem;
    int* hist  = (int*)(smem + TPART*8);
    int* scn   = hist + NBMAX;
    int* cnt2  = scn + NBMAX;
    int* baseg = cnt2 + NBMAX;
    const int t0 = blockIdx.x * TPART;
    if (t < NBMAX){ hist[t] = 0; cnt2[t] = 0; }
    __syncthreads();
    #pragma unroll 4
    for (int k = 0; k < 8; ++k){
      int i = t0 + (k << 10) + t;
      if (i < E) atomicAdd(&hist[dst[i] >> 8], 1);
    }
    __syncthreads();
    if (t < NBMAX) scn[t] = hist[t];
    __syncthreads();
    for (int o = 1; o < NBMAX; o <<= 1){
      int a = (t >= o && t < NBMAX) ? scn[t-o] : 0;
      __syncthreads();
      if (t < NBMAX) scn[t] += a;
      __syncthreads();
    }
    if (t < NB) baseg[t] = hist[t] ? atomicAdd(&bcur[t], hist[t]) : 0;
    __syncthreads();
    #pragma unroll 4
    for (int k = 0; k < 8; ++k){
      int i = t0 + (k << 10) + t;
      if (i < E){
        int d = dst[i], b = d >> 8;
        int r = atomicAdd(&cnt2[b], 1);
        stage[scn[b] - hist[b] + r] = make_int2(((d & 255) << 17) | src[i], __float_as_int(w[i]));
      }
    }
    __syncthreads();
    int wv = t >> 6, ln = t & 63;
    for (int b = wv; b < NB; b += 16){
      int c = hist[b];
      if (!c) continue;
      int lo = scn[b] - c, gb = baseg[b];
      for (int s2 = ln; s2 < c; s2 += 64) part[gb + s2] = stage[lo + s2];
    }
  } else {
    // ---- GEMM1 role: Y(bf16) = A(f32) @ W0, 16 waves = 256 rows/block ----
    unsigned short* Wt = (unsigned short*)smem;
    for (int i = t; i < 128*16; i += 1024){
      int r = i >> 4, c = (i & 15) << 3;
      *(uint4*)(Wt + r*WPITCH + c) = *(const uint4*)(Wg + r*128 + c);
    }
    __syncthreads();
    const int lane = t & 63, wv = t >> 6;
    const int r0 = (blockIdx.x - PB)*256 + wv*16;
    int rA = r0 + (lane & 15); if (rA > n-1) rA = n-1;
    const int kq = (lane >> 4) << 3;             // 0,8,16,24
    f32x4 acc[8] = {};
    #pragma unroll
    for (int kk = 0; kk < 4; ++kk){
      const float* ap = A + (size_t)rA*NF + kk*32 + kq;
      float4 a0 = *(const float4*)ap;
      float4 a1 = *(const float4*)(ap + 4);
      bf16x8 af;
      af[0]=(short)f2bf(a0.x); af[1]=(short)f2bf(a0.y); af[2]=(short)f2bf(a0.z); af[3]=(short)f2bf(a0.w);
      af[4]=(short)f2bf(a1.x); af[5]=(short)f2bf(a1.y); af[6]=(short)f2bf(a1.z); af[7]=(short)f2bf(a1.w);
      const unsigned short* wp = Wt + (lane & 15)*WPITCH + kk*32 + kq;
      #pragma unroll
      for (int nt = 0; nt < 8; ++nt){
        bf16x8 bf = *(const bf16x8*)(wp + nt*16*WPITCH);
        acc[nt] = __builtin_amdgcn_mfma_f32_16x16x32_bf16(af, bf, acc[nt], 0, 0, 0);
      }
    }
    const int rb = r0 + ((lane >> 4) << 2);      // D: col=nt*16+(lane&15), row=rb+j
    #pragma unroll
    for (int j = 0; j < 4; ++j){
      int rg = rb + j;
      if (rg < n){
        unsigned short* yp = Y + (size_t)rg*NF + (lane & 15);
        #pragma unroll
        for (int nt = 0; nt < 8; ++nt) yp[nt*16] = f2bf(acc[nt][j]);
      }
    }
  }
}

// ---------- 2. exact fill per bucket: noff[] (s,e per node) + csr[] ----------
__global__ __launch_bounds__(512) void k_fill2(const int2* __restrict__ part, const int* __restrict__ bcur,
    int2* __restrict__ noff, int2* __restrict__ csr, int N){
  __shared__ int deg[256], scn[256], c2[256];
  const int b = blockIdx.x, t = threadIdx.x;
  const int base = b * BCAP;
  const int cnt = bcur[b] - base;
  const int d0 = b << 8;
  const int nd = min(256, N - d0);
  if (t < 256){ deg[t] = 0; c2[t] = 0; }
  __syncthreads();
  for (int s = t; s < cnt; s += 512) atomicAdd(&deg[(part[base+s].x >> 17) & 255], 1);
  __syncthreads();
  if (t < 256) scn[t] = deg[t];
  __syncthreads();
  for (int o = 1; o < 256; o <<= 1){
    int a = (t < 256 && t >= o) ? scn[t-o] : 0;
    __syncthreads();
    if (t < 256) scn[t] += a;
    __syncthreads();
  }
  if (t < nd) noff[d0 + t] = make_int2(base + scn[t] - deg[t], base + scn[t]);
  __syncthreads();
  for (int s = t; s < cnt; s += 512){
    int2 rec = part[base + s];
    int dl = (rec.x >> 17) & 255;
    int p = base + scn[dl] - deg[dl] + atomicAdd(&c2[dl], 1);
    csr[p] = make_int2(rec.x & 0x1FFFF, rec.y);
  }
}

// ---------- 3. FUSED SpMM1 + bias + ReLU + GEMM2 (MFMA): g = bf16(relu(A@y+b0) @ W1) ----------
// 16 waves = 16 nodes/block. Each wave: proven spmm body -> hb row into LDS.
// Barrier; wave 0 runs gemm2's 16-row MFMA tile from LDS and writes g.
__global__ __launch_bounds__(1024, 2) void k_spmm_g2(const unsigned short* __restrict__ y, const int2* __restrict__ csr,
    const int2* __restrict__ noff, const float* __restrict__ bias, const unsigned short* __restrict__ Wg,
    unsigned short* __restrict__ G, int n){
  __shared__ unsigned short Wt[64*WPITCH];     // 17.4 KB (W1^T bf16)
  __shared__ unsigned short hbS[16*WPITCH];    // 4.3 KB (16 hb rows, pitch 136)
  const int t = threadIdx.x;
  for (int i = t; i < 64*16; i += 1024){
    int r = i >> 4, c = (i & 15) << 3;
    *(uint4*)(Wt + r*WPITCH + c) = *(const uint4*)(Wg + r*128 + c);
  }
  const int wv = t >> 6, lane = t & 63;
  const int wid = blockIdx.x*16 + wv;
  const int half = lane >> 5, li = lane & 31;
  if (wid < n){
    const int2 se = noff[wid];
    const int s = __builtin_amdgcn_readfirstlane(se.x);
    const int e = __builtin_amdgcn_readfirstlane(se.y);
    const unsigned liOff = (unsigned)li << 3;
    const char* yb = (const char*)y;
    float a0x[2]={0.f,0.f}, a0y[2]={0.f,0.f}, a1x[2]={0.f,0.f}, a1y[2]={0.f,0.f};
    const int deg = e - s;

#define RELU_FMA(VV, WW)                                                      \
    _Pragma("unroll")                                                         \
    for (int k = 0; k < 8; ++k){                                              \
      a0x[k&1] = fmaf(WW[k], bflo(VV[k].x), a0x[k&1]);                        \
      a0y[k&1] = fmaf(WW[k], bfhi(VV[k].x), a0y[k&1]);                        \
      a1x[k&1] = fmaf(WW[k], bflo(VV[k].y), a1x[k&1]);                        \
      a1y[k&1] = fmaf(WW[k], bfhi(VV[k].y), a1y[k&1]);                        \
    }

    if (deg > 0 && deg <= 16){
      i32x16 rA, rB;
      sload16_issue(rA, csr + s);
      sload16_issue(rB, csr + s + 8);
      swait2(rA, rB);
      const int jbh = s + (half << 3);
      unsigned offk[8]; float wk[8];
      #pragma unroll
      for (int k = 0; k < 8; ++k){
        int r  = half ? rB[2*k]   : rA[2*k];
        int wb = half ? rB[2*k+1] : rA[2*k+1];
        r = ((unsigned)r < (unsigned)n) ? r : 0;           // clamp garbage rows (SALU)
        offk[k] = ((unsigned)r << 8) + liOff;
        wk[k] = (jbh + k < e) ? __int_as_float(wb) : 0.f;
      }
      uint2 v[8];
      #pragma unroll
      for (int k = 0; k < 8; ++k) v[k] = *(const uint2*)(yb + offk[k]);
      __builtin_amdgcn_sched_barrier(0);
      RELU_FMA(v, wk)
    } else if (deg > 16 && deg <= 32){
      i32x16 rA0, rB0, rA1, rB1;
      sload16_issue(rA0, csr + s);
      sload16_issue(rB0, csr + s + 8);
      sload16_issue(rA1, csr + e - 16);
      sload16_issue(rB1, csr + e - 8);
      swait4(rA0, rB0, rA1, rB1);
      const int lo1 = s + 16;
      const int t1 = (e - 16) + (half << 3);
      unsigned off0[8], off1[8]; float wk0[8], wk1[8];
      #pragma unroll
      for (int k = 0; k < 8; ++k){
        int r0v = half ? rB0[2*k] : rA0[2*k];
        int w0v = half ? rB0[2*k+1] : rA0[2*k+1];
        off0[k] = ((unsigned)r0v << 8) + liOff;
        wk0[k] = __int_as_float(w0v);                          // fully in-range
        int r1v = half ? rB1[2*k] : rA1[2*k];
        int w1v = half ? rB1[2*k+1] : rA1[2*k+1];
        off1[k] = ((unsigned)r1v << 8) + liOff;
        wk1[k] = (t1 + k >= lo1) ? __int_as_float(w1v) : 0.f;  // lo-mask overlap
      }
      uint2 v0[8], v1[8];
      #pragma unroll
      for (int k = 0; k < 8; ++k) v0[k] = *(const uint2*)(yb + off0[k]);
      #pragma unroll
      for (int k = 0; k < 8; ++k) v1[k] = *(const uint2*)(yb + off1[k]);
      __builtin_amdgcn_sched_barrier(0);
      RELU_FMA(v0, wk0)
      RELU_FMA(v1, wk1)
    } else if (deg > 32){
      int jb = s;
      const int nfull = deg >> 4;
      for (int b = 0; b < nfull; ++b, jb += 16){
        i32x16 rA, rB;
        sload16_issue(rA, csr + jb);
        sload16_issue(rB, csr + jb + 8);
        swait2(rA, rB);
        unsigned offk[8]; float wk[8];
        #pragma unroll
        for (int k = 0; k < 8; ++k){
          int r  = half ? rB[2*k]   : rA[2*k];
          int wb = half ? rB[2*k+1] : rA[2*k+1];
          offk[k] = ((unsigned)r << 8) + liOff;
          wk[k] = __int_as_float(wb);
        }
        uint2 v[8];
        #pragma unroll
        for (int k = 0; k < 8; ++k) v[k] = *(const uint2*)(yb + offk[k]);
        __builtin_amdgcn_sched_barrier(0);
        RELU_FMA(v, wk)
      }
      if (jb < e){
        i32x16 rA, rB;
        sload16_issue(rA, csr + e - 16);
        sload16_issue(rB, csr + e - 8);
        swait2(rA, rB);
        const int t1 = (e - 16) + (half << 3);
        unsigned offk[8]; float wk[8];
        #pragma unroll
        for (int k = 0; k < 8; ++k){
          int r  = half ? rB[2*k]   : rA[2*k];
          int wb = half ? rB[2*k+1] : rA[2*k+1];
          offk[k] = ((unsigned)r << 8) + liOff;
          wk[k] = (t1 + k >= jb) ? __int_as_float(wb) : 0.f;
        }
        uint2 v[8];
        #pragma unroll
        for (int k = 0; k < 8; ++k) v[k] = *(const uint2*)(yb + offk[k]);
        __builtin_amdgcn_sched_barrier(0);
        RELU_FMA(v, wk)
      }
    }
#undef RELU_FMA
    float o0 = a0x[0]+a0x[1], o1 = a0y[0]+a0y[1], o2 = a1x[0]+a1x[1], o3 = a1y[0]+a1y[1];
    o0 += __shfl_xor(o0, 32); o1 += __shfl_xor(o1, 32);
    o2 += __shfl_xor(o2, 32); o3 += __shfl_xor(o3, 32);
    float4 bb = ((const float4*)bias)[li];
    o0 = fmaxf(o0 + bb.x, 0.f); o1 = fmaxf(o1 + bb.y, 0.f);
    o2 = fmaxf(o2 + bb.z, 0.f); o3 = fmaxf(o3 + bb.w, 0.f);
    if (half == 0){
      uint2 p;
      p.x = (unsigned)f2bf(o0) | ((unsigned)f2bf(o1) << 16);
      p.y = (unsigned)f2bf(o2) | ((unsigned)f2bf(o3) << 16);
      *(uint2*)(hbS + wv*WPITCH + li*4) = p;     // row into LDS
    }
  }
  __syncthreads();
  if (wv == 0){
    // gemm2 tile: 16 rows (hbS) x 64 cols, from LDS
    const int kq = (lane >> 4) << 3;
    f32x4 acc[4] = {};
    #pragma unroll
    for (int kk = 0; kk < 4; ++kk){
      bf16x8 af = *(const bf16x8*)(hbS + (lane & 15)*WPITCH + kk*32 + kq);
      const unsigned short* wp = Wt + (lane & 15)*WPITCH + kk*32 + kq;
      #pragma unroll
      for (int nt = 0; nt < 4; ++nt){
        bf16x8 bf = *(const bf16x8*)(wp + nt*16*WPITCH);
        acc[nt] = __builtin_amdgcn_mfma_f32_16x16x32_bf16(af, bf, acc[nt], 0, 0, 0);
      }
    }
    const int rb = (lane >> 4) << 2;
    #pragma unroll
    for (int j = 0; j < 4; ++j){
      int rg = blockIdx.x*16 + rb + j;
      if (rg < n){
        unsigned short* gp = G + (size_t)rg*NC + (lane & 15);
        #pragma unroll
        for (int nt = 0; nt < 4; ++nt) gp[nt*16] = f2bf(acc[nt][j]);
      }
    }
  }
}

// ---------- 4. SpMM2 + bias + log_softmax: out = ls(A@g + b1) ----------
__global__ __launch_bounds__(256, 6) void k_spmm_ls(const unsigned short* __restrict__ g, const int2* __restrict__ csr,
    const int2* __restrict__ noff, const float* __restrict__ bias, float* __restrict__ out, int n){
  int wid  = (blockIdx.x * 256 + threadIdx.x) >> 6;
  int lane = threadIdx.x & 63;
  if (wid >= n) return;
  const int2 se = noff[wid];
  const int s = __builtin_amdgcn_readfirstlane(se.x);
  const int e = __builtin_amdgcn_readfirstlane(se.y);
  const int half = lane >> 5, li = lane & 31;
  const unsigned liOff = (unsigned)li << 2;
  const char* gb = (const char*)g;
  float z0[2]={0.f,0.f}, z1[2]={0.f,0.f};
  const int deg = e - s;

#define LS_FMA(VV, WW)                                                        \
    _Pragma("unroll")                                                         \
    for (int k = 0; k < 8; ++k){                                              \
      z0[k&1] = fmaf(WW[k], bflo(VV[k]), z0[k&1]);                            \
      z1[k&1] = fmaf(WW[k], bfhi(VV[k]), z1[k&1]);                            \
    }

  if (deg > 0 && deg <= 16){
    i32x16 rA, rB;
    sload16_issue(rA, csr + s);
    sload16_issue(rB, csr + s + 8);
    swait2(rA, rB);
    const int jbh = s + (half << 3);
    unsigned offk[8]; float wk[8];
    #pragma unroll
    for (int k = 0; k < 8; ++k){
      int r  = half ? rB[2*k]   : rA[2*k];
      int wb = half ? rB[2*k+1] : rA[2*k+1];
      r = ((unsigned)r < (unsigned)n) ? r : 0;           // clamp garbage rows (SALU)
      offk[k] = ((unsigned)r << 7) + liOff;
      wk[k] = (jbh + k < e) ? __int_as_float(wb) : 0.f;
    }
    unsigned v[8];
    #pragma unroll
    for (int k = 0; k < 8; ++k) v[k] = *(const unsigned*)(gb + offk[k]);
    __builtin_amdgcn_sched_barrier(0);
    LS_FMA(v, wk)
  } else if (deg > 16 && deg <= 32){
    i32x16 rA0, rB0, rA1, rB1;
    sload16_issue(rA0, csr + s);
    sload16_issue(rB0, csr + s + 8);
    sload16_issue(rA1, csr + e - 16);
    sload16_issue(rB1, csr + e - 8);
    swait4(rA0, rB0, rA1, rB1);
    const int lo1 = s + 16;
    const int t1 = (e - 16) + (half << 3);
    unsigned off0[8], off1[8]; float wk0[8], wk1[8];
    #pragma unroll
    for (int k = 0; k < 8; ++k){
      int r0v = half ? rB0[2*k] : rA0[2*k];
      int w0v = half ? rB0[2*k+1] : rA0[2*k+1];
      off0[k] = ((unsigned)r0v << 7) + liOff;
      wk0[k] = __int_as_float(w0v);
      int r1v = half ? rB1[2*k] : rA1[2*k];
      int w1v = half ? rB1[2*k+1] : rA1[2*k+1];
      off1[k] = ((unsigned)r1v << 7) + liOff;
      wk1[k] = (t1 + k >= lo1) ? __int_as_float(w1v) : 0.f;
    }
    unsigned v0[8], v1[8];
    #pragma unroll
    for (int k = 0; k < 8; ++k) v0[k] = *(const unsigned*)(gb + off0[k]);
    #pragma unroll
    for (int k = 0; k < 8; ++k) v1[k] = *(const unsigned*)(gb + off1[k]);
    __builtin_amdgcn_sched_barrier(0);
    LS_FMA(v0, wk0)
    LS_FMA(v1, wk1)
  } else if (deg > 32){
    int jb = s;
    const int nfull = deg >> 4;
    for (int b = 0; b < nfull; ++b, jb += 16){
      i32x16 rA, rB;
      sload16_issue(rA, csr + jb);
      sload16_issue(rB, csr + jb + 8);
      swait2(rA, rB);
      unsigned offk[8]; float wk[8];
      #pragma unroll
      for (int k = 0; k < 8; ++k){
        int r  = half ? rB[2*k]   : rA[2*k];
        int wb = half ? rB[2*k+1] : rA[2*k+1];
        offk[k] = ((unsigned)r << 7) + liOff;
        wk[k] = __int_as_float(wb);
      }
      unsigned v[8];
      #pragma unroll
      for (int k = 0; k < 8; ++k) v[k] = *(const unsigned*)(gb + offk[k]);
      __builtin_amdgcn_sched_barrier(0);
      LS_FMA(v, wk)
    }
    if (jb < e){
      i32x16 rA, rB;
      sload16_issue(rA, csr + e - 16);
      sload16_issue(rB, csr + e - 8);
      swait2(rA, rB);
      const int t1 = (e - 16) + (half << 3);
      unsigned offk[8]; float wk[8];
      #pragma unroll
      for (int k = 0; k < 8; ++k){
        int r  = half ? rB[2*k]   : rA[2*k];
        int wb = half ? rB[2*k+1] : rA[2*k+1];
        offk[k] = ((unsigned)r << 7) + liOff;
        wk[k] = (t1 + k >= jb) ? __int_as_float(wb) : 0.f;
      }
      unsigned v[8];
      #pragma unroll
      for (int k = 0; k < 8; ++k) v[k] = *(const unsigned*)(gb + offk[k]);
      __builtin_amdgcn_sched_barrier(0);
      LS_FMA(v, wk)
    }
  }
#undef LS_FMA
  float zz0 = z0[0]+z0[1], zz1 = z1[0]+z1[1];
  zz0 += __shfl_xor(zz0, 32); zz1 += __shfl_xor(zz1, 32);
  float2 bb = ((const float2*)bias)[li];
  zz0 += bb.x; zz1 += bb.y;
  float m = fmaxf(zz0, zz1);
  for (int o = 16; o; o >>= 1) m = fmaxf(m, __shfl_xor(m, o));
  float sum = expf(zz0 - m) + expf(zz1 - m);
  for (int o = 16; o; o >>= 1) sum += __shfl_xor(sum, o);
  float lg = logf(sum);
  if (half == 0)
    *(float2*)(out + (size_t)wid * NC + li*2) = make_float2(zz0 - m - lg, zz1 - m - lg);
}

extern "C" void kernel_launch(void* const* d_in, const int* in_sizes, int n_in,
                              void* d_out, int out_size, void* d_ws, size_t ws_size,
                              hipStream_t stream){
  const float* x  = (const float*)d_in[0];
  const int* esrc = (const int*)d_in[1];
  const int* edst = (const int*)d_in[2];
  const float* ew = (const float*)d_in[3];
  const float* W0 = (const float*)d_in[4];
  const float* b0 = (const float*)d_in[5];
  const float* W1 = (const float*)d_in[6];
  const float* b1 = (const float*)d_in[7];
  float* out = (float*)d_out;

  const int N = in_sizes[0] / NF;
  const int E = in_sizes[1];
  const int NB = (N + 255) >> 8;            // 391 buckets of 256 dsts

  char* ws = (char*)d_ws;
  size_t o = 0;
  int*  bcur  = (int*) (ws + o); o = alignup(o + NBMAX*4);
  int2* noff  = (int2*)(ws + o); o = alignup(o + (size_t)N*8);
  unsigned short* W0t = (unsigned short*)(ws + o); o = alignup(o + 128*128*2);
  unsigned short* W1t = (unsigned short*)(ws + o); o = alignup(o + 128*64*2);
  int2* part  = (int2*)(ws + o); o = alignup(o + (size_t)NB*BCAP*8);
  int2* csr   = (int2*)(ws + o); o = alignup(o + (size_t)NB*BCAP*8 + 256);
  unsigned short* y = (unsigned short*)(ws + o); o = alignup(o + (size_t)N*NF*2);  // bf16 x@W0
  unsigned short* g = (unsigned short*)(ws + o); o = alignup(o + (size_t)N*NC*2);  // bf16 hb@W1

  const int pb  = (E + TPART-1)/TPART;      // partition-role blocks
  const int gb1 = (N + 255)/256;            // gemm1-role blocks (256 rows each)

  k_cvtW <<<96, 256, 0, stream>>>(W0, W1, W0t, W1t, bcur, NB);
  k_partg<<<pb + gb1, 1024, 0, stream>>>(esrc, edst, ew, bcur, part, E, NB, pb,
                                         x, W0t, y, N);          // build || y = bf16(x@W0)
  k_fill2<<<NB, 512, 0, stream>>>(part, bcur, noff, csr, N);

  const int sg = (N + 15)/16;               // 16 nodes per 1024-thr block
  const int sb = (N + 3)/4;

  k_spmm_g2<<<sg, 1024, 0, stream>>>(y, csr, noff, b0, W1t, g, N); // g = bf16(relu(Ay+b0)@W1)
  k_spmm_ls<<<sb, 256, 0, stream>>>(g, csr, noff, b1, out, N);     // out = log_softmax(A g + b1)
}

// Round 22
// 167.324 us; speedup vs baseline: 1.0679x; 1.0679x over previous
//
#include <hip/hip_runtime.h>

#define NF 128
#define NC 64
#define NBMAX 512          // max dst-buckets (N/256 = 391 for N=100000)
#define TPART 8192         // edges per k_part block
#define BCAP 5120          // fixed bucket capacity: mean 4092 + 16 sigma
#define WPITCH 136         // LDS W^T pitch in bf16: 272B rows, 2-way banks (free)

static inline size_t alignup(size_t x){ return (x + 255) & ~(size_t)255; }

typedef __attribute__((ext_vector_type(8))) short bf16x8;
typedef __attribute__((ext_vector_type(4))) float f32x4;
typedef __attribute__((ext_vector_type(16))) int i32x16;

__device__ __forceinline__ unsigned short f2bf(float f){
  unsigned u = __float_as_uint(f);
  u += 0x7fffu + ((u >> 16) & 1u);       // round-to-nearest-even
  return (unsigned short)(u >> 16);
}
__device__ __forceinline__ float bflo(unsigned u){ return __uint_as_float(u << 16); }
__device__ __forceinline__ float bfhi(unsigned u){ return __uint_as_float(u & 0xffff0000u); }

// issue 8 edge records into SGPRs (no wait); SMEM needs only dword alignment
__device__ __forceinline__ void sload16_issue(i32x16& r, const int2* p){
  asm volatile("s_load_dwordx16 %0, %1, 0x0" : "=s"(r) : "s"(p));
}
__device__ __forceinline__ void swait2(i32x16& a, i32x16& b){
  asm volatile("s_waitcnt lgkmcnt(0)" : "+s"(a), "+s"(b));
}
__device__ __forceinline__ void swait4(i32x16& a, i32x16& b, i32x16& c, i32x16& d){
  asm volatile("s_waitcnt lgkmcnt(0)" : "+s"(a), "+s"(b), "+s"(c), "+s"(d));
}

// ---------- 0. pre-convert weights to transposed bf16 + init bucket cursors ----------
__global__ __launch_bounds__(256) void k_cvtW(const float* __restrict__ W0, const float* __restrict__ W1,
                                              unsigned short* __restrict__ W0t, unsigned short* __restrict__ W1t,
                                              int* __restrict__ bcur, int NB){
  int t = blockIdx.x*256 + threadIdx.x;
  if (t < NB) bcur[t] = t * BCAP;             // fixed-capacity bases
  if (t < 128*128){ int k = t >> 7, c = t & 127; W0t[c*128 + k] = f2bf(W0[t]); }
  int u = t - 128*128;
  if (u >= 0 && u < 128*64){ int k = u >> 6, c = u & 63; W1t[c*128 + k] = f2bf(W1[u]); }
}

// ---------- 1. FUSED: partition (blocks < PB)  ||  GEMM1 MFMA (blocks >= PB) ----------
__global__ __launch_bounds__(1024, 4) void k_partg(const int* __restrict__ src, const int* __restrict__ dst,
    const float* __restrict__ w, int* __restrict__ bcur, int2* __restrict__ part, int E, int NB, int PB,
    const float* __restrict__ A, const unsigned short* __restrict__ Wg, unsigned short* __restrict__ Y, int n){
  __shared__ __align__(16) char smem[TPART*8 + NBMAX*16];   // 72 KB
  const int t = threadIdx.x;
  if ((int)blockIdx.x < PB){
    // ---- partition role ----
    int2* stage = (int2*)smem;
    int* hist  = (int*)(smem + TPART*8);
    int* scn   = hist + NBMAX;
    int* cnt2  = scn + NBMAX;
    int* baseg = cnt2 + NBMAX;
    const int t0 = blockIdx.x * TPART;
    if (t < NBMAX){ hist[t] = 0; cnt2[t] = 0; }
    __syncthreads();
    #pragma unroll 4
    for (int k = 0; k < 8; ++k){
      int i = t0 + (k << 10) + t;
      if (i < E) atomicAdd(&hist[dst[i] >> 8], 1);
    }
    __syncthreads();
    if (t < NBMAX) scn[t] = hist[t];
    __syncthreads();
    for (int o = 1; o < NBMAX; o <<= 1){
      int a = (t >= o && t < NBMAX) ? scn[t-o] : 0;
      __syncthreads();
      if (t < NBMAX) scn[t] += a;
      __syncthreads();
    }
    if (t < NB) baseg[t] = hist[t] ? atomicAdd(&bcur[t], hist[t]) : 0;
    __syncthreads();
    #pragma unroll 4
    for (int k = 0; k < 8; ++k){
      int i = t0 + (k << 10) + t;
      if (i < E){
        int d = dst[i], b = d >> 8;
        int r = atomicAdd(&cnt2[b], 1);
        stage[scn[b] - hist[b] + r] = make_int2(((d & 255) << 17) | src[i], __float_as_int(w[i]));
      }
    }
    __syncthreads();
    int wv = t >> 6, ln = t & 63;
    for (int b = wv; b < NB; b += 16){
      int c = hist[b];
      if (!c) continue;
      int lo = scn[b] - c, gb = baseg[b];
      for (int s2 = ln; s2 < c; s2 += 64) part[gb + s2] = stage[lo + s2];
    }
  } else {
    // ---- GEMM1 role: Y(bf16) = A(f32) @ W0, 16 waves = 256 rows/block ----
    unsigned short* Wt = (unsigned short*)smem;
    for (int i = t; i < 128*16; i += 1024){
      int r = i >> 4, c = (i & 15) << 3;
      *(uint4*)(Wt + r*WPITCH + c) = *(const uint4*)(Wg + r*128 + c);
    }
    __syncthreads();
    const int lane = t & 63, wv = t >> 6;
    const int r0 = (blockIdx.x - PB)*256 + wv*16;
    int rA = r0 + (lane & 15); if (rA > n-1) rA = n-1;
    const int kq = (lane >> 4) << 3;             // 0,8,16,24
    f32x4 acc[8] = {};
    #pragma unroll
    for (int kk = 0; kk < 4; ++kk){
      const float* ap = A + (size_t)rA*NF + kk*32 + kq;
      float4 a0 = *(const float4*)ap;
      float4 a1 = *(const float4*)(ap + 4);
      bf16x8 af;
      af[0]=(short)f2bf(a0.x); af[1]=(short)f2bf(a0.y); af[2]=(short)f2bf(a0.z); af[3]=(short)f2bf(a0.w);
      af[4]=(short)f2bf(a1.x); af[5]=(short)f2bf(a1.y); af[6]=(short)f2bf(a1.z); af[7]=(short)f2bf(a1.w);
      const unsigned short* wp = Wt + (lane & 15)*WPITCH + kk*32 + kq;
      #pragma unroll
      for (int nt = 0; nt < 8; ++nt){
        bf16x8 bf = *(const bf16x8*)(wp + nt*16*WPITCH);
        acc[nt] = __builtin_amdgcn_mfma_f32_16x16x32_bf16(af, bf, acc[nt], 0, 0, 0);
      }
    }
    const int rb = r0 + ((lane >> 4) << 2);      // D: col=nt*16+(lane&15), row=rb+j
    #pragma unroll
    for (int j = 0; j < 4; ++j){
      int rg = rb + j;
      if (rg < n){
        unsigned short* yp = Y + (size_t)rg*NF + (lane & 15);
        #pragma unroll
        for (int nt = 0; nt < 8; ++nt) yp[nt*16] = f2bf(acc[nt][j]);
      }
    }
  }
}

// ---------- 2. exact fill per bucket: noff[] (s,e per node) + csr[] ----------
__global__ __launch_bounds__(512) void k_fill2(const int2* __restrict__ part, const int* __restrict__ bcur,
    int2* __restrict__ noff, int2* __restrict__ csr, int N){
  __shared__ int deg[256], scn[256], c2[256];
  const int b = blockIdx.x, t = threadIdx.x;
  const int base = b * BCAP;
  const int cnt = bcur[b] - base;
  const int d0 = b << 8;
  const int nd = min(256, N - d0);
  if (t < 256){ deg[t] = 0; c2[t] = 0; }
  __syncthreads();
  for (int s = t; s < cnt; s += 512) atomicAdd(&deg[(part[base+s].x >> 17) & 255], 1);
  __syncthreads();
  if (t < 256) scn[t] = deg[t];
  __syncthreads();
  for (int o = 1; o < 256; o <<= 1){
    int a = (t < 256 && t >= o) ? scn[t-o] : 0;
    __syncthreads();
    if (t < 256) scn[t] += a;
    __syncthreads();
  }
  if (t < nd) noff[d0 + t] = make_int2(base + scn[t] - deg[t], base + scn[t]);
  __syncthreads();
  for (int s = t; s < cnt; s += 512){
    int2 rec = part[base + s];
    int dl = (rec.x >> 17) & 255;
    int p = base + scn[dl] - deg[dl] + atomicAdd(&c2[dl], 1);
    csr[p] = make_int2(rec.x & 0x1FFFF, rec.y);
  }
}

// ---------- GEMM2 (MFMA): G(bf16) = h(bf16) @ W1  (n x 128 @ 128 x 64) ----------
__global__ __launch_bounds__(256) void k_gemm2(const unsigned short* __restrict__ Ab, const unsigned short* __restrict__ Wg,
                                               unsigned short* __restrict__ G, int n){
  __shared__ unsigned short Wt[64*WPITCH];     // 17.4 KB
  const int tid = threadIdx.x;
  for (int i = tid; i < 64*16; i += 256){
    int r = i >> 4, c = (i & 15) << 3;
    *(uint4*)(Wt + r*WPITCH + c) = *(const uint4*)(Wg + r*128 + c);
  }
  __syncthreads();
  const int lane = tid & 63, wv = tid >> 6;
  const int r0 = blockIdx.x*64 + wv*16;
  int rA = r0 + (lane & 15); if (rA > n-1) rA = n-1;
  const int kq = (lane >> 4) << 3;
  f32x4 acc[4] = {};
  #pragma unroll
  for (int kk = 0; kk < 4; ++kk){
    bf16x8 af = *(const bf16x8*)(Ab + (size_t)rA*NF + kk*32 + kq);
    const unsigned short* wp = Wt + (lane & 15)*WPITCH + kk*32 + kq;
    #pragma unroll
    for (int nt = 0; nt < 4; ++nt){
      bf16x8 bf = *(const bf16x8*)(wp + nt*16*WPITCH);
      acc[nt] = __builtin_amdgcn_mfma_f32_16x16x32_bf16(af, bf, acc[nt], 0, 0, 0);
    }
  }
  const int rb = r0 + ((lane >> 4) << 2);
  #pragma unroll
  for (int j = 0; j < 4; ++j){
    int rg = rb + j;
    if (rg < n){
      unsigned short* gp = G + (size_t)rg*NC + (lane & 15);
      #pragma unroll
      for (int nt = 0; nt < 4; ++nt) gp[nt*16] = f2bf(acc[nt][j]);
    }
  }
}

// ---------- SpMM1 + bias + ReLU: h(bf16) = relu(A@y + b0) ----------
// Scalar-fmaf body; one scalar-wait per node (deg<=32); half-wave gathers.
// deg<=16 over-reads into uninit bucket pad: w index-masked, row SALU-clamped.
__global__ __launch_bounds__(256, 6) void k_spmm_relu(const unsigned short* __restrict__ y, const int2* __restrict__ csr,
    const int2* __restrict__ noff, const float* __restrict__ bias, unsigned short* __restrict__ h, int n){
  int wid  = (blockIdx.x * 256 + threadIdx.x) >> 6;
  int lane = threadIdx.x & 63;
  if (wid >= n) return;
  const int2 se = noff[wid];
  const int s = __builtin_amdgcn_readfirstlane(se.x);
  const int e = __builtin_amdgcn_readfirstlane(se.y);
  const int half = lane >> 5, li = lane & 31;
  const unsigned liOff = (unsigned)li << 3;
  const char* yb = (const char*)y;
  float a0x[2]={0.f,0.f}, a0y[2]={0.f,0.f}, a1x[2]={0.f,0.f}, a1y[2]={0.f,0.f};
  const int deg = e - s;

#define RELU_FMA(VV, WW)                                                      \
    _Pragma("unroll")                                                         \
    for (int k = 0; k < 8; ++k){                                              \
      a0x[k&1] = fmaf(WW[k], bflo(VV[k].x), a0x[k&1]);                        \
      a0y[k&1] = fmaf(WW[k], bfhi(VV[k].x), a0y[k&1]);                        \
      a1x[k&1] = fmaf(WW[k], bflo(VV[k].y), a1x[k&1]);                        \
      a1y[k&1] = fmaf(WW[k], bfhi(VV[k].y), a1y[k&1]);                        \
    }

  if (deg > 0 && deg <= 16){
    i32x16 rA, rB;
    sload16_issue(rA, csr + s);
    sload16_issue(rB, csr + s + 8);
    swait2(rA, rB);
    const int jbh = s + (half << 3);
    unsigned offk[8]; float wk[8];
    #pragma unroll
    for (int k = 0; k < 8; ++k){
      int r  = half ? rB[2*k]   : rA[2*k];
      int wb = half ? rB[2*k+1] : rA[2*k+1];
      r = ((unsigned)r < (unsigned)n) ? r : 0;           // clamp garbage rows (SALU)
      offk[k] = ((unsigned)r << 8) + liOff;
      wk[k] = (jbh + k < e) ? __int_as_float(wb) : 0.f;
    }
    uint2 v[8];
    #pragma unroll
    for (int k = 0; k < 8; ++k) v[k] = *(const uint2*)(yb + offk[k]);
    __builtin_amdgcn_sched_barrier(0);
    RELU_FMA(v, wk)
  } else if (deg > 16 && deg <= 32){
    i32x16 rA0, rB0, rA1, rB1;
    sload16_issue(rA0, csr + s);
    sload16_issue(rB0, csr + s + 8);
    sload16_issue(rA1, csr + e - 16);
    sload16_issue(rB1, csr + e - 8);
    swait4(rA0, rB0, rA1, rB1);
    const int lo1 = s + 16;
    const int t1 = (e - 16) + (half << 3);
    unsigned off0[8], off1[8]; float wk0[8], wk1[8];
    #pragma unroll
    for (int k = 0; k < 8; ++k){
      int r0v = half ? rB0[2*k] : rA0[2*k];
      int w0v = half ? rB0[2*k+1] : rA0[2*k+1];
      off0[k] = ((unsigned)r0v << 8) + liOff;
      wk0[k] = __int_as_float(w0v);                          // fully in-range
      int r1v = half ? rB1[2*k] : rA1[2*k];
      int w1v = half ? rB1[2*k+1] : rA1[2*k+1];
      off1[k] = ((unsigned)r1v << 8) + liOff;
      wk1[k] = (t1 + k >= lo1) ? __int_as_float(w1v) : 0.f;  // lo-mask overlap
    }
    uint2 v0[8], v1[8];
    #pragma unroll
    for (int k = 0; k < 8; ++k) v0[k] = *(const uint2*)(yb + off0[k]);
    #pragma unroll
    for (int k = 0; k < 8; ++k) v1[k] = *(const uint2*)(yb + off1[k]);
    __builtin_amdgcn_sched_barrier(0);
    RELU_FMA(v0, wk0)
    RELU_FMA(v1, wk1)
  } else if (deg > 32){
    int jb = s;
    const int nfull = deg >> 4;
    for (int b = 0; b < nfull; ++b, jb += 16){
      i32x16 rA, rB;
      sload16_issue(rA, csr + jb);
      sload16_issue(rB, csr + jb + 8);
      swait2(rA, rB);
      unsigned offk[8]; float wk[8];
      #pragma unroll
      for (int k = 0; k < 8; ++k){
        int r  = half ? rB[2*k]   : rA[2*k];
        int wb = half ? rB[2*k+1] : rA[2*k+1];
        offk[k] = ((unsigned)r << 8) + liOff;
        wk[k] = __int_as_float(wb);
      }
      uint2 v[8];
      #pragma unroll
      for (int k = 0; k < 8; ++k) v[k] = *(const uint2*)(yb + offk[k]);
      __builtin_amdgcn_sched_barrier(0);
      RELU_FMA(v, wk)
    }
    if (jb < e){
      i32x16 rA, rB;
      sload16_issue(rA, csr + e - 16);
      sload16_issue(rB, csr + e - 8);
      swait2(rA, rB);
      const int t1 = (e - 16) + (half << 3);
      unsigned offk[8]; float wk[8];
      #pragma unroll
      for (int k = 0; k < 8; ++k){
        int r  = half ? rB[2*k]   : rA[2*k];
        int wb = half ? rB[2*k+1] : rA[2*k+1];
        offk[k] = ((unsigned)r << 8) + liOff;
        wk[k] = (t1 + k >= jb) ? __int_as_float(wb) : 0.f;
      }
      uint2 v[8];
      #pragma unroll
      for (int k = 0; k < 8; ++k) v[k] = *(const uint2*)(yb + offk[k]);
      __builtin_amdgcn_sched_barrier(0);
      RELU_FMA(v, wk)
    }
  }
#undef RELU_FMA
  float o0 = a0x[0]+a0x[1], o1 = a0y[0]+a0y[1], o2 = a1x[0]+a1x[1], o3 = a1y[0]+a1y[1];
  o0 += __shfl_xor(o0, 32); o1 += __shfl_xor(o1, 32);
  o2 += __shfl_xor(o2, 32); o3 += __shfl_xor(o3, 32);
  float4 bb = ((const float4*)bias)[li];
  o0 = fmaxf(o0 + bb.x, 0.f); o1 = fmaxf(o1 + bb.y, 0.f);
  o2 = fmaxf(o2 + bb.z, 0.f); o3 = fmaxf(o3 + bb.w, 0.f);
  if (half == 0){
    uint2 p;
    p.x = (unsigned)f2bf(o0) | ((unsigned)f2bf(o1) << 16);
    p.y = (unsigned)f2bf(o2) | ((unsigned)f2bf(o3) << 16);
    *(uint2*)(h + (size_t)wid * NF + li*4) = p;
  }
}

// ---------- SpMM2 + bias + log_softmax: out = ls(A@g + b1) ----------
__global__ __launch_bounds__(256, 6) void k_spmm_ls(const unsigned short* __restrict__ g, const int2* __restrict__ csr,
    const int2* __restrict__ noff, const float* __restrict__ bias, float* __restrict__ out, int n){
  int wid  = (blockIdx.x * 256 + threadIdx.x) >> 6;
  int lane = threadIdx.x & 63;
  if (wid >= n) return;
  const int2 se = noff[wid];
  const int s = __builtin_amdgcn_readfirstlane(se.x);
  const int e = __builtin_amdgcn_readfirstlane(se.y);
  const int half = lane >> 5, li = lane & 31;
  const unsigned liOff = (unsigned)li << 2;
  const char* gb = (const char*)g;
  float z0[2]={0.f,0.f}, z1[2]={0.f,0.f};
  const int deg = e - s;

#define LS_FMA(VV, WW)                                                        \
    _Pragma("unroll")                                                         \
    for (int k = 0; k < 8; ++k){                                              \
      z0[k&1] = fmaf(WW[k], bflo(VV[k]), z0[k&1]);                            \
      z1[k&1] = fmaf(WW[k], bfhi(VV[k]), z1[k&1]);                            \
    }

  if (deg > 0 && deg <= 16){
    i32x16 rA, rB;
    sload16_issue(rA, csr + s);
    sload16_issue(rB, csr + s + 8);
    swait2(rA, rB);
    const int jbh = s + (half << 3);
    unsigned offk[8]; float wk[8];
    #pragma unroll
    for (int k = 0; k < 8; ++k){
      int r  = half ? rB[2*k]   : rA[2*k];
      int wb = half ? rB[2*k+1] : rA[2*k+1];
      r = ((unsigned)r < (unsigned)n) ? r : 0;           // clamp garbage rows (SALU)
      offk[k] = ((unsigned)r << 7) + liOff;
      wk[k] = (jbh + k < e) ? __int_as_float(wb) : 0.f;
    }
    unsigned v[8];
    #pragma unroll
    for (int k = 0; k < 8; ++k) v[k] = *(const unsigned*)(gb + offk[k]);
    __builtin_amdgcn_sched_barrier(0);
    LS_FMA(v, wk)
  } else if (deg > 16 && deg <= 32){
    i32x16 rA0, rB0, rA1, rB1;
    sload16_issue(rA0, csr + s);
    sload16_issue(rB0, csr + s + 8);
    sload16_issue(rA1, csr + e - 16);
    sload16_issue(rB1, csr + e - 8);
    swait4(rA0, rB0, rA1, rB1);
    const int lo1 = s + 16;
    const int t1 = (e - 16) + (half << 3);
    unsigned off0[8], off1[8]; float wk0[8], wk1[8];
    #pragma unroll
    for (int k = 0; k < 8; ++k){
      int r0v = half ? rB0[2*k] : rA0[2*k];
      int w0v = half ? rB0[2*k+1] : rA0[2*k+1];
      off0[k] = ((unsigned)r0v << 7) + liOff;
      wk0[k] = __int_as_float(w0v);
      int r1v = half ? rB1[2*k] : rA1[2*k];
      int w1v = half ? rB1[2*k+1] : rA1[2*k+1];
      off1[k] = ((unsigned)r1v << 7) + liOff;
      wk1[k] = (t1 + k >= lo1) ? __int_as_float(w1v) : 0.f;
    }
    unsigned v0[8], v1[8];
    #pragma unroll
    for (int k = 0; k < 8; ++k) v0[k] = *(const unsigned*)(gb + off0[k]);
    #pragma unroll
    for (int k = 0; k < 8; ++k) v1[k] = *(const unsigned*)(gb + off1[k]);
    __builtin_amdgcn_sched_barrier(0);
    LS_FMA(v0, wk0)
    LS_FMA(v1, wk1)
  } else if (deg > 32){
    int jb = s;
    const int nfull = deg >> 4;
    for (int b = 0; b < nfull; ++b, jb += 16){
      i32x16 rA, rB;
      sload16_issue(rA, csr + jb);
      sload16_issue(rB, csr + jb + 8);
      swait2(rA, rB);
      unsigned offk[8]; float wk[8];
      #pragma unroll
      for (int k = 0; k < 8; ++k){
        int r  = half ? rB[2*k]   : rA[2*k];
        int wb = half ? rB[2*k+1] : rA[2*k+1];
        offk[k] = ((unsigned)r << 7) + liOff;
        wk[k] = __int_as_float(wb);
      }
      unsigned v[8];
      #pragma unroll
      for (int k = 0; k < 8; ++k) v[k] = *(const unsigned*)(gb + offk[k]);
      __builtin_amdgcn_sched_barrier(0);
      LS_FMA(v, wk)
    }
    if (jb < e){
      i32x16 rA, rB;
      sload16_issue(rA, csr + e - 16);
      sload16_issue(rB, csr + e - 8);
      swait2(rA, rB);
      const int t1 = (e - 16) + (half << 3);
      unsigned offk[8]; float wk[8];
      #pragma unroll
      for (int k = 0; k < 8; ++k){
        int r  = half ? rB[2*k]   : rA[2*k];
        int wb = half ? rB[2*k+1] : rA[2*k+1];
        offk[k] = ((unsigned)r << 7) + liOff;
        wk[k] = (t1 + k >= jb) ? __int_as_float(wb) : 0.f;
      }
      unsigned v[8];
      #pragma unroll
      for (int k = 0; k < 8; ++k) v[k] = *(const unsigned*)(gb + offk[k]);
      __builtin_amdgcn_sched_barrier(0);
      LS_FMA(v, wk)
    }
  }
#undef LS_FMA
  float zz0 = z0[0]+z0[1], zz1 = z1[0]+z1[1];
  zz0 += __shfl_xor(zz0, 32); zz1 += __shfl_xor(zz1, 32);
  float2 bb = ((const float2*)bias)[li];
  zz0 += bb.x; zz1 += bb.y;
  float m = fmaxf(zz0, zz1);
  for (int o = 16; o; o >>= 1) m = fmaxf(m, __shfl_xor(m, o));
  float sum = expf(zz0 - m) + expf(zz1 - m);
  for (int o = 16; o; o >>= 1) sum += __shfl_xor(sum, o);
  float lg = logf(sum);
  if (half == 0)
    *(float2*)(out + (size_t)wid * NC + li*2) = make_float2(zz0 - m - lg, zz1 - m - lg);
}

extern "C" void kernel_launch(void* const* d_in, const int* in_sizes, int n_in,
                              void* d_out, int out_size, void* d_ws, size_t ws_size,
                              hipStream_t stream){
  const float* x  = (const float*)d_in[0];
  const int* esrc = (const int*)d_in[1];
  const int* edst = (const int*)d_in[2];
  const float* ew = (const float*)d_in[3];
  const float* W0 = (const float*)d_in[4];
  const float* b0 = (const float*)d_in[5];
  const float* W1 = (const float*)d_in[6];
  const float* b1 = (const float*)d_in[7];
  float* out = (float*)d_out;

  const int N = in_sizes[0] / NF;
  const int E = in_sizes[1];
  const int NB = (N + 255) >> 8;            // 391 buckets of 256 dsts

  char* ws = (char*)d_ws;
  size_t o = 0;
  int*  bcur  = (int*) (ws + o); o = alignup(o + NBMAX*4);
  int2* noff  = (int2*)(ws + o); o = alignup(o + (size_t)N*8);
  unsigned short* W0t = (unsigned short*)(ws + o); o = alignup(o + 128*128*2);
  unsigned short* W1t = (unsigned short*)(ws + o); o = alignup(o + 128*64*2);
  int2* part  = (int2*)(ws + o); o = alignup(o + (size_t)NB*BCAP*8);
  int2* csr   = (int2*)(ws + o); o = alignup(o + (size_t)NB*BCAP*8 + 256);
  unsigned short* y  = (unsigned short*)(ws + o); o = alignup(o + (size_t)N*NF*2);  // bf16; reused as g
  unsigned short* hb = (unsigned short*)(ws + o); o = alignup(o + (size_t)N*NF*2);  // bf16 h
  unsigned short* g = y;  // y dead after k_spmm_relu

  const int pb  = (E + TPART-1)/TPART;      // partition-role blocks
  const int gb1 = (N + 255)/256;            // gemm1-role blocks (256 rows each)

  k_cvtW <<<96, 256, 0, stream>>>(W0, W1, W0t, W1t, bcur, NB);
  k_partg<<<pb + gb1, 1024, 0, stream>>>(esrc, edst, ew, bcur, part, E, NB, pb,
                                         x, W0t, y, N);        // build || y = bf16(x@W0)
  k_fill2<<<NB, 512, 0, stream>>>(part, bcur, noff, csr, N);

  const int gb = (N + 63)/64;
  const int sb = (N + 3)/4;

  k_spmm_relu<<<sb, 256, 0, stream>>>(y, csr, noff, b0, hb, N); // hb = bf16(relu(A y + b0))
  k_gemm2<<<gb, 256, 0, stream>>>(hb, W1t, g, N);               // g = bf16(hb @ W1)  [MFMA]
  k_spmm_ls<<<sb, 256, 0, stream>>>(g, csr, noff, b1, out, N);  // out = log_softmax(A g + b1)
}